// Round 3
// baseline (187.806 us; speedup 1.0000x reference)
//
#include <hip/hip_runtime.h>
#include <hip/hip_bf16.h>

typedef __bf16 bf16x8 __attribute__((ext_vector_type(8)));
typedef float f32x4 __attribute__((ext_vector_type(4)));

typedef __attribute__((address_space(1))) void GAS;
typedef __attribute__((address_space(3))) void LAS;
#define GLOAD16(gp, lp) __builtin_amdgcn_global_load_lds((GAS*)(gp), (LAS*)(lp), 16, 0, 0)

#define NB 4096
#define ND 512
#define NKT 24  // 3 segments * (512/64) K-tiles of 64

// ---------------- Kernel 1: row-normalize + split into bf16 hi/lo; zero stats ----------------
__global__ __launch_bounds__(256) void nrm_split_k(const float* __restrict__ x,
                                                   __bf16* __restrict__ hi,
                                                   __bf16* __restrict__ lo,
                                                   float* __restrict__ stats) {
    if (blockIdx.x == 0 && threadIdx.x < 21) stats[threadIdx.x] = 0.0f;  // 20 stats + ticket
    const int wid = threadIdx.x >> 6, lane = threadIdx.x & 63;
    const int row = blockIdx.x * 4 + wid;
    const float4* xr = reinterpret_cast<const float4*>(x + (size_t)row * ND);
    float4 v0 = xr[lane * 2 + 0];
    float4 v1 = xr[lane * 2 + 1];
    float xv[8] = {v0.x, v0.y, v0.z, v0.w, v1.x, v1.y, v1.z, v1.w};
    float ss = 0.0f;
#pragma unroll
    for (int j = 0; j < 8; ++j) ss += xv[j] * xv[j];
#pragma unroll
    for (int off = 32; off > 0; off >>= 1) ss += __shfl_xor(ss, off);
    const float rn = 1.0f / fmaxf(sqrtf(ss), 1e-12f);
    bf16x8 h, l;
#pragma unroll
    for (int j = 0; j < 8; ++j) {
        float xn = xv[j] * rn;
        __bf16 hb = (__bf16)xn;
        h[j] = hb;
        l[j] = (__bf16)(xn - (float)hb);
    }
    reinterpret_cast<bf16x8*>(hi + (size_t)row * ND)[lane] = h;
    reinterpret_cast<bf16x8*>(lo + (size_t)row * ND)[lane] = l;
}

// ------- Kernel 2: 256^2-tile 8-phase GEMM + fused histogram + fused finalize -------
__global__ __launch_bounds__(512, 2) void gemm_stat_k(const __bf16* __restrict__ hi,
                                                      const __bf16* __restrict__ lo,
                                                      const int* __restrict__ targets,
                                                      const float* __restrict__ acc_sum,
                                                      float* __restrict__ stats,
                                                      float* __restrict__ out) {
    // [slot][A=0/B=1][half][128 rows x 64 cols bf16], rows 128B, XOR-swizzled (16B granule)
    __shared__ __align__(16) __bf16 lds[2][2][2][128 * 64];
    __shared__ int tgtR[256], tgtC[256];
    __shared__ float red_s[8][10], red_c[8][10];

    const int bid = blockIdx.x;
    const int swz = (bid & 7) * 32 + (bid >> 3);  // 256 blocks, 8 XCDs, bijective
    const int by = swz >> 4, bx = swz & 15;
    const int row0 = by * 256, col0 = bx * 256;
    const int tid = threadIdx.x, lane = tid & 63;
    const int wid = tid >> 6, wr = wid >> 2, wc = wid & 3;  // 2 x 4 waves

    if (tid < 256) tgtR[tid] = targets[row0 + tid];
    else           tgtC[tid - 256] = targets[col0 + tid - 256];

    // staging: half-tile = 128x64 bf16 = 1024 x 16B chunks; thread handles chunks tid, tid+512
    const int c0 = tid, c1 = tid + 512;
    const int r0c = c0 >> 3, x0 = ((c0 & 7) ^ (r0c & 7)) * 8;  // inverse-swizzled source col
    const int r1c = c1 >> 3, x1 = ((c1 & 7) ^ (r1c & 7)) * 8;

    // half-tile stream order per K-tile: h=0:A-half0, 1:B-half0, 2:B-half1, 3:A-half1
    auto STAGE = [&](int kt, int h) {
        const int slot = kt & 1, seg = kt >> 3, kcol = (kt & 7) * 64;
        const bool isA = (h == 0) || (h == 3);
        const int half = (h >= 2) ? 1 : 0;
        const __bf16* mat = isA ? ((seg == 2) ? lo : hi) : ((seg == 1) ? lo : hi);
        const int brow = (isA ? row0 : col0) + half * 128;
        __bf16* dst = &lds[slot][isA ? 0 : 1][half][0];
        GLOAD16(mat + (size_t)(brow + r0c) * ND + kcol + x0, dst + c0 * 8);
        GLOAD16(mat + (size_t)(brow + r1c) * ND + kcol + x1, dst + c1 * 8);
    };

    // precomputed swizzled LDS element offsets (per thread, registers)
    const int fr = lane & 15, hi16 = lane >> 4;
    const int Bhalf = wc >> 1;
    int offA[2][4], offB[2][4];
#pragma unroll
    for (int kh = 0; kh < 2; ++kh)
#pragma unroll
        for (int q = 0; q < 4; ++q) {
            const int ra = wr * 64 + q * 16 + fr;
            offA[kh][q] = ra * 64 + ((kh * 32 + hi16 * 8) ^ ((ra & 7) << 3));
            const int rb = (wc & 1) * 64 + q * 16 + fr;
            offB[kh][q] = rb * 64 + ((kh * 32 + hi16 * 8) ^ ((rb & 7) << 3));
        }

    const f32x4 fzero = {0.0f, 0.0f, 0.0f, 0.0f};
    f32x4 acc[8][4];
#pragma unroll
    for (int a = 0; a < 8; ++a)
#pragma unroll
        for (int n = 0; n < 4; ++n) acc[a][n] = fzero;

    // prologue: tile 0's 4 half-tiles; first 3 must land, A-half1 stays in flight
    STAGE(0, 0); STAGE(0, 1); STAGE(0, 2); STAGE(0, 3);
    asm volatile("s_waitcnt vmcnt(2)" ::: "memory");
    __builtin_amdgcn_s_barrier();

    for (int kt = 0; kt < NKT; ++kt) {
        const int slot = kt & 1;
        const __bf16* bA0 = &lds[slot][0][0][0];
        const __bf16* bA1 = &lds[slot][0][1][0];
        const __bf16* bB  = &lds[slot][1][Bhalf][0];
        const bool more = (kt + 1 < NKT);
#pragma unroll
        for (int f = 0; f < 4; ++f) {  // phase: Mh = f>>1, kh = f&1
            const int Mh = f >> 1, kh = f & 1;
            if (more) STAGE(kt + 1, f);  // top-of-phase prefetch, always other slot
            const __bf16* bA = Mh ? bA1 : bA0;
            bf16x8 af[4], bf[4];
#pragma unroll
            for (int q = 0; q < 4; ++q)
                af[q] = *reinterpret_cast<const bf16x8*>(bA + offA[kh][q]);
#pragma unroll
            for (int n = 0; n < 4; ++n)
                bf[n] = *reinterpret_cast<const bf16x8*>(bB + offB[kh][n]);
            __builtin_amdgcn_s_barrier();  // B1
            __builtin_amdgcn_s_setprio(1);
#pragma unroll
            for (int q = 0; q < 4; ++q)
#pragma unroll
                for (int n = 0; n < 4; ++n)
                    acc[Mh * 4 + q][n] = __builtin_amdgcn_mfma_f32_16x16x32_bf16(
                        af[q], bf[n], acc[Mh * 4 + q][n], 0, 0, 0);
            __builtin_amdgcn_s_setprio(0);
            if (f == 1) {  // own A-half1 (read at f=2,3) must be resident
                if (more) asm volatile("s_waitcnt vmcnt(4)" ::: "memory");
                else      asm volatile("s_waitcnt vmcnt(0)" ::: "memory");
            }
            if (f == 3 && more) {  // next tile's {A0,B0,B1} must be resident
                asm volatile("s_waitcnt vmcnt(2)" ::: "memory");
            }
            __builtin_amdgcn_s_barrier();  // B2
        }
    }

    // ---- epilogue: per-lane histogram of g=|cos-label| over 128 elements ----
    int tcv[4];
#pragma unroll
    for (int n = 0; n < 4; ++n) tcv[n] = tgtC[wc * 64 + n * 16 + fr];

    constexpr float E[11] = {0.0f, 0.1f, 0.2f, 0.3f, 0.4f, 0.5f,
                             0.6f, 0.7f, 0.8f, 0.9f, 1.0f + 1e-6f};
    float sacc[10], cacc[10];
#pragma unroll
    for (int b = 0; b < 10; ++b) { sacc[b] = 0.0f; cacc[b] = 0.0f; }

    const int rB = wr * 64 + hi16 * 4;
#pragma unroll
    for (int a = 0; a < 8; ++a) {
        int trv[4];
#pragma unroll
        for (int r = 0; r < 4; ++r) trv[r] = tgtR[(a >> 2) * 128 + rB + (a & 3) * 16 + r];
#pragma unroll
        for (int n = 0; n < 4; ++n) {
            f32x4 v = acc[a][n];
            const int tc = tcv[n];
#pragma unroll
            for (int r = 0; r < 4; ++r) {
                const float label = (trv[r] == tc) ? 1.0f : 0.0f;
                const float g = fabsf(v[r] - label);
                const float g2 = g * g;
                bool prev = true;
#pragma unroll
                for (int b = 0; b < 10; ++b) {
                    const bool ge = (g >= E[b + 1]);
                    const bool in = prev && (!ge);
                    sacc[b] += in ? g2 : 0.0f;
                    cacc[b] += in ? 1.0f : 0.0f;
                    prev = ge;
                }
            }
        }
    }

#pragma unroll
    for (int b = 0; b < 10; ++b) {
        float sv = sacc[b], cv = cacc[b];
#pragma unroll
        for (int off = 32; off > 0; off >>= 1) {
            sv += __shfl_xor(sv, off);
            cv += __shfl_xor(cv, off);
        }
        if (lane == 0) { red_s[wid][b] = sv; red_c[wid][b] = cv; }
    }
    __syncthreads();
    if (tid < 10) {
        float s = 0.0f, c = 0.0f;
#pragma unroll
        for (int w = 0; w < 8; ++w) { s += red_s[w][tid]; c += red_c[w][tid]; }
        atomicAdd(&stats[tid], s);
        atomicAdd(&stats[10 + tid], c);
        __threadfence();  // order this thread's adds before the ticket
    }
    __syncthreads();

    // ---- fused finalize: last block computes the loss ----
    if (tid == 0) {
        int old = atomicAdd((int*)&stats[20], 1);
        if (old == 255) {
            __threadfence();
            const float tot = 16777216.0f;  // 4096^2
            double num = 0.0, valid = 0.0;
#pragma unroll
            for (int b = 0; b < 10; ++b) {
                float sb = atomicAdd(&stats[b], 0.0f);       // coherent read
                float cnt = atomicAdd(&stats[10 + b], 0.0f); // coherent read
                float accn = 0.5f * acc_sum[b] + 0.5f * cnt;
                float w = tot / (accn + 1e-6f);
                num += (double)sb * (double)w;
                valid += (double)cnt;
            }
            out[0] = (valid > 0.0) ? (float)(num / valid / 16777216.0) : 0.0f;
        }
    }
}

extern "C" void kernel_launch(void* const* d_in, const int* in_sizes, int n_in,
                              void* d_out, int out_size, void* d_ws, size_t ws_size,
                              hipStream_t stream) {
    const float* x = (const float*)d_in[0];
    const float* acc_sum = (const float*)d_in[1];
    const int* targets = (const int*)d_in[2];
    float* out = (float*)d_out;

    char* ws = (char*)d_ws;
    const size_t mat_bytes = (size_t)NB * ND * sizeof(__bf16);  // 4 MB
    __bf16* hi = (__bf16*)ws;
    __bf16* lo = (__bf16*)(ws + mat_bytes);
    float* stats = (float*)(ws + 2 * mat_bytes);  // 20 stats + ticket

    nrm_split_k<<<NB / 4, 256, 0, stream>>>(x, hi, lo, stats);
    gemm_stat_k<<<256, 512, 0, stream>>>(hi, lo, targets, acc_sum, stats, out);
}

// Round 4
// 161.935 us; speedup vs baseline: 1.1598x; 1.1598x over previous
//
#include <hip/hip_runtime.h>
#include <hip/hip_bf16.h>

typedef __bf16 bf16x8 __attribute__((ext_vector_type(8)));
typedef float f32x16 __attribute__((ext_vector_type(16)));

typedef __attribute__((address_space(1))) void GAS;
typedef __attribute__((address_space(3))) void LAS;
#define GLOAD16(gp, lp) __builtin_amdgcn_global_load_lds((GAS*)(gp), (LAS*)(lp), 16, 0, 0)

#define NB 4096
#define NDU 1024  // concat [hi | lo] width
#define NKT 16    // 1024 / 64

// ---------------- Kernel 1: row-normalize + split into u = [hi | lo]; zero stats ----------------
__global__ __launch_bounds__(256) void nrm_split_k(const float* __restrict__ x,
                                                   __bf16* __restrict__ u,
                                                   float* __restrict__ stats) {
    if (blockIdx.x == 0 && threadIdx.x < 21) stats[threadIdx.x] = 0.0f;  // 20 stats + ticket
    const int wid = threadIdx.x >> 6, lane = threadIdx.x & 63;
    const int row = blockIdx.x * 4 + wid;
    const float4* xr = reinterpret_cast<const float4*>(x + (size_t)row * 512);
    float4 v0 = xr[lane * 2 + 0];
    float4 v1 = xr[lane * 2 + 1];
    float xv[8] = {v0.x, v0.y, v0.z, v0.w, v1.x, v1.y, v1.z, v1.w};
    float ss = 0.0f;
#pragma unroll
    for (int j = 0; j < 8; ++j) ss += xv[j] * xv[j];
#pragma unroll
    for (int off = 32; off > 0; off >>= 1) ss += __shfl_xor(ss, off);
    const float rn = 1.0f / fmaxf(sqrtf(ss), 1e-12f);
    bf16x8 h, l;
#pragma unroll
    for (int j = 0; j < 8; ++j) {
        float xn = xv[j] * rn;
        __bf16 hb = (__bf16)xn;
        h[j] = hb;
        l[j] = (__bf16)(xn - (float)hb);  // xn == hi + lo to ~2^-17
    }
    reinterpret_cast<bf16x8*>(u + (size_t)row * NDU)[lane] = h;
    reinterpret_cast<bf16x8*>(u + (size_t)row * NDU + 512)[lane] = l;
}

// ------- Kernel 2: 256^2-tile GEMM cos = u u^T (K=1024), 32x32x16 MFMA, fused histogram+finalize -------
__global__ __launch_bounds__(512, 2) void gemm_stat_k(const __bf16* __restrict__ u,
                                                      const int* __restrict__ targets,
                                                      const float* __restrict__ acc_sum,
                                                      float* __restrict__ stats,
                                                      float* __restrict__ out) {
    // [slot][half: 0=A0 1=A1 2=B0 3=B1][128 rows x 64 cols bf16], XOR-swizzled 16B granule
    __shared__ __align__(16) __bf16 lds[2][4][128 * 64];
    __shared__ int tgtR[256], tgtC[256];
    __shared__ float red_s[8][10], red_c[8][10];

    const int bid = blockIdx.x;
    const int swz = (bid & 7) * 32 + (bid >> 3);  // 256 blocks, 8 XCDs, bijective
    const int by = swz >> 4, bx = swz & 15;
    const int row0 = by * 256, col0 = bx * 256;
    const int tid = threadIdx.x, lane = tid & 63;
    const int wid = tid >> 6, wr = wid >> 2, wc = wid & 3;  // 2 x 4 waves

    if (tid < 256) tgtR[tid] = targets[row0 + tid];
    else           tgtC[tid - 256] = targets[col0 + tid - 256];

    // staging: half-tile = 128x64 bf16 = 1024 x 16B chunks; this thread owns chunks tid, tid+512
    const int c0 = tid, c1 = tid + 512;
    const int r0c = c0 >> 3, x0 = ((c0 & 7) ^ (r0c & 7)) * 8;  // inverse-swizzled source col
    const int r1c = c1 >> 3, x1 = ((c1 & 7) ^ (r1c & 7)) * 8;

    // half-tile stream index g: kt = g>>2, h = g&3 (0=A0,1=A1,2=B0,3=B1)
    auto STAGE = [&](int g) {
        const int kt = g >> 2, h = g & 3;
        const int slot = kt & 1, kcol = kt * 64;
        const int brow = ((h < 2) ? row0 : col0) + (h & 1) * 128;
        __bf16* dst = &lds[slot][h][0];
        GLOAD16(u + (size_t)(brow + r0c) * NDU + kcol + x0, dst + c0 * 8);
        GLOAD16(u + (size_t)(brow + r1c) * NDU + kcol + x1, dst + c1 * 8);
    };

    // precomputed LDS element offsets (32x32x16 fragments)
    const int l31 = lane & 31, hi2 = lane >> 5;
    int rowAe[4], rowBe[2], colE[4];
#pragma unroll
    for (int m = 0; m < 4; ++m) rowAe[m] = (m * 32 + l31) * 64;
#pragma unroll
    for (int n = 0; n < 2; ++n) rowBe[n] = ((wc & 1) * 64 + n * 32 + l31) * 64;
#pragma unroll
    for (int ks = 0; ks < 4; ++ks) colE[ks] = (ks * 16 + hi2 * 8) ^ ((lane & 7) << 3);

    const f32x16 fz = {0,0,0,0, 0,0,0,0, 0,0,0,0, 0,0,0,0};
    f32x16 acc[4][2];
#pragma unroll
    for (int m = 0; m < 4; ++m)
#pragma unroll
        for (int n = 0; n < 2; ++n) acc[m][n] = fz;

    // prologue: kt0's 4 half-tiles + kt1.A0 in flight
    STAGE(0); STAGE(1); STAGE(2); STAGE(3); STAGE(4);
    asm volatile("s_waitcnt vmcnt(2)" ::: "memory");
    __builtin_amdgcn_s_barrier();
    __builtin_amdgcn_sched_barrier(0);

    for (int kt = 0; kt < NKT; ++kt) {
        const int slot = kt & 1;
        const __bf16* lA = &lds[slot][wr][0];          // this wave's A half
        const __bf16* lB = &lds[slot][2 + (wc >> 1)][0];  // this wave's B half
#pragma unroll
        for (int f = 0; f < 2; ++f) {  // phase = 2 k-steps (K=32)
            bf16x8 af[4][2], bf[2][2];
#pragma unroll
            for (int kq = 0; kq < 2; ++kq) {
                const int ks = 2 * f + kq;
#pragma unroll
                for (int m = 0; m < 4; ++m)
                    af[m][kq] = *reinterpret_cast<const bf16x8*>(lA + rowAe[m] + colE[ks]);
#pragma unroll
                for (int n = 0; n < 2; ++n)
                    bf[n][kq] = *reinterpret_cast<const bf16x8*>(lB + rowBe[n] + colE[ks]);
            }
            {  // prefetch stream: 2 half-tiles per phase, 5 half-tiles ahead
                const int g = 4 * kt + 2 * f + 5;
                if (g < 4 * NKT) STAGE(g);
                if (g + 1 < 4 * NKT) STAGE(g + 1);
            }
            __builtin_amdgcn_s_barrier();  // B1
            __builtin_amdgcn_sched_barrier(0);
            __builtin_amdgcn_s_setprio(1);
#pragma unroll
            for (int kq = 0; kq < 2; ++kq)
#pragma unroll
                for (int m = 0; m < 4; ++m)
#pragma unroll
                    for (int n = 0; n < 2; ++n)
                        acc[m][n] = __builtin_amdgcn_mfma_f32_32x32x16_bf16(
                            af[m][kq], bf[n][kq], acc[m][n], 0, 0, 0);
            __builtin_amdgcn_s_setprio(0);
            __builtin_amdgcn_sched_barrier(0);
            if (f == 1) {  // K-tile boundary: next tile fully resident
                if (kt < NKT - 2)       asm volatile("s_waitcnt vmcnt(2)" ::: "memory");
                else if (kt == NKT - 2) asm volatile("s_waitcnt vmcnt(0)" ::: "memory");
            }
            __builtin_amdgcn_s_barrier();  // B2
            __builtin_amdgcn_sched_barrier(0);
        }
    }

    // ---- epilogue: per-lane histogram of g=|cos-label| over 128 elements ----
    // 32x32 C/D layout: col = lane&31, row = (reg&3) + 8*(reg>>2) + 4*(lane>>5)
    int tcv[2];
#pragma unroll
    for (int n = 0; n < 2; ++n) tcv[n] = tgtC[wc * 64 + n * 32 + l31];

    constexpr float E[11] = {0.0f, 0.1f, 0.2f, 0.3f, 0.4f, 0.5f,
                             0.6f, 0.7f, 0.8f, 0.9f, 1.0f + 1e-6f};
    float sacc[10], cacc[10];
#pragma unroll
    for (int b = 0; b < 10; ++b) { sacc[b] = 0.0f; cacc[b] = 0.0f; }

#pragma unroll
    for (int m = 0; m < 4; ++m) {
        const int rbase = wr * 128 + m * 32 + hi2 * 4;
        int trv[16];
#pragma unroll
        for (int reg = 0; reg < 16; ++reg)
            trv[reg] = tgtR[rbase + (reg >> 2) * 8 + (reg & 3)];
#pragma unroll
        for (int n = 0; n < 2; ++n) {
            f32x16 v = acc[m][n];
            const int tc = tcv[n];
#pragma unroll
            for (int reg = 0; reg < 16; ++reg) {
                const float label = (trv[reg] == tc) ? 1.0f : 0.0f;
                const float g = fabsf(v[reg] - label);
                const float g2 = g * g;
                bool prev = true;
#pragma unroll
                for (int b = 0; b < 10; ++b) {
                    const bool ge = (g >= E[b + 1]);
                    const bool in = prev && (!ge);
                    sacc[b] += in ? g2 : 0.0f;
                    cacc[b] += in ? 1.0f : 0.0f;
                    prev = ge;
                }
            }
        }
    }

#pragma unroll
    for (int b = 0; b < 10; ++b) {
        float sv = sacc[b], cv = cacc[b];
#pragma unroll
        for (int off = 32; off > 0; off >>= 1) {
            sv += __shfl_xor(sv, off);
            cv += __shfl_xor(cv, off);
        }
        if (lane == 0) { red_s[wid][b] = sv; red_c[wid][b] = cv; }
    }
    __syncthreads();
    if (tid < 10) {
        float s = 0.0f, c = 0.0f;
#pragma unroll
        for (int w = 0; w < 8; ++w) { s += red_s[w][tid]; c += red_c[w][tid]; }
        atomicAdd(&stats[tid], s);
        atomicAdd(&stats[10 + tid], c);
        __threadfence();
    }
    __syncthreads();

    // ---- fused finalize: last block computes the loss ----
    if (tid == 0) {
        int old = atomicAdd((int*)&stats[20], 1);
        if (old == 255) {
            __threadfence();
            const float tot = 16777216.0f;  // 4096^2
            double num = 0.0, valid = 0.0;
#pragma unroll
            for (int b = 0; b < 10; ++b) {
                float sb = atomicAdd(&stats[b], 0.0f);
                float cnt = atomicAdd(&stats[10 + b], 0.0f);
                float accn = 0.5f * acc_sum[b] + 0.5f * cnt;
                float w = tot / (accn + 1e-6f);
                num += (double)sb * (double)w;
                valid += (double)cnt;
            }
            out[0] = (valid > 0.0) ? (float)(num / valid / 16777216.0) : 0.0f;
        }
    }
}

extern "C" void kernel_launch(void* const* d_in, const int* in_sizes, int n_in,
                              void* d_out, int out_size, void* d_ws, size_t ws_size,
                              hipStream_t stream) {
    const float* x = (const float*)d_in[0];
    const float* acc_sum = (const float*)d_in[1];
    const int* targets = (const int*)d_in[2];
    float* out = (float*)d_out;

    char* ws = (char*)d_ws;
    __bf16* u = (__bf16*)ws;                                   // 4096 x 1024 bf16 = 8 MB
    float* stats = (float*)(ws + (size_t)NB * NDU * sizeof(__bf16));  // 20 stats + ticket

    nrm_split_k<<<NB / 4, 256, 0, stream>>>(x, u, stats);
    gemm_stat_k<<<256, 512, 0, stream>>>(u, targets, acc_sum, stats, out);
}